// Round 7
// baseline (163.239 us; speedup 1.0000x reference)
//
#include <hip/hip_runtime.h>
#include <hip/hip_bf16.h>
#include <stdint.h>

typedef unsigned short u16;
typedef __attribute__((ext_vector_type(8))) short short8;
typedef __attribute__((ext_vector_type(4))) float floatx4;

#define N_IMG 4
#define C_IN  2048
#define HW    1024
#define KK    9
#define O_OUT 256
#define NPIX  4096          // N_IMG*HW
#define M_PAD  2560         // 16 M-tiles x 160 rows (2304 proj + 81 conv + pad)
#define H_ROWS 2432         // H rows actually stored (proj 2304 + conv 81 + pad)
#define K_DIM  2048
#define BN_EPS 1e-5f

// workspace offsets (bytes), 256-aligned
#define OFF_A    0u                // A: 2560*2048*2 = 10485760
#define OFF_XT   10485760u         // XT: 4096*2048*2 = 16777216
#define OFF_H    27262976u         // H: 2432*4096*2 = 19922944
#define OFF_SRAW 47185920u         // sraw: 36864*4
#define OFF_STAT 47333376u

// fp32 -> bf16 bits, round-to-nearest-even
__device__ __forceinline__ u16 f2b(float f) {
    unsigned u = __float_as_uint(f);
    return (u16)((u + 0x7FFFu + ((u >> 16) & 1u)) >> 16);
}

__device__ __forceinline__ float b2f(u16 h) {
    return __uint_as_float((unsigned)h << 16);
}

__device__ __forceinline__ void load8f(const float* base, size_t eidx, u16* out) {
    const float* p = base + eidx;
    float4 a = ((const float4*)p)[0];
    float4 b = ((const float4*)p)[1];
    float f[8] = {a.x, a.y, a.z, a.w, b.x, b.y, b.z, b.w};
#pragma unroll
    for (int j = 0; j < 8; ++j) out[j] = f2b(f[j]);
}

// ---------------- merged staging kernel (R10-validated, unchanged) ----------------
__global__ void build_all(const float* __restrict__ x, const float* __restrict__ wgt,
                          const float* __restrict__ cw, u16* __restrict__ xt,
                          u16* __restrict__ A, float* __restrict__ stats) {
    __shared__ __align__(16) u16 lds[9 * 2056];
    int b = blockIdx.x, t = threadIdx.x;
    if (b < 2048) {
        int c0 = (b & 31) * 64, p0 = ((b >> 5) & 15) * 64, n = b >> 9;
        int rp = t >> 3;                // channel-pair 0..31
        int pv = (t & 7) * 8;           // pixel group
        u16 h0[8], h1[8];
        load8f(x, (size_t)(n * C_IN + c0 + 2 * rp) * HW + p0 + pv, h0);
        load8f(x, (size_t)(n * C_IN + c0 + 2 * rp + 1) * HW + p0 + pv, h1);
        unsigned* l32 = (unsigned*)lds;   // [64 pixels][stride 35 u32]
#pragma unroll
        for (int j = 0; j < 8; ++j)
            l32[(pv + j) * 35 + rp] = (unsigned)h0[j] | ((unsigned)h1[j] << 16);
        __syncthreads();
        int pr = t >> 3, cq = (t & 7) * 4;   // pixel, u32-quad (8 channels)
        unsigned o0[4], o1[4];
#pragma unroll
        for (int i = 0; i < 4; ++i) {
            o0[i] = l32[pr * 35 + cq + i];
            o1[i] = l32[(pr + 32) * 35 + cq + i];
        }
        *(uint4*)(xt + (size_t)(n * HW + p0 + pr) * K_DIM + c0 + cq * 2) = *(uint4*)o0;
        *(uint4*)(xt + (size_t)(n * HW + p0 + pr + 32) * K_DIM + c0 + cq * 2) = *(uint4*)o1;
    } else if (b < 2304) {
        int o = b - 2048;
        size_t base = (size_t)o * 18432;   // weight[o][c][l], e = c*9+l
        for (int i = 0; i < 9; ++i) {
            int e0 = (t + i * 256) * 8;
            u16 hv[8];
            load8f(wgt, base + e0, hv);
#pragma unroll
            for (int j = 0; j < 8; ++j) {
                int e = e0 + j;
                int c = e / 9, l = e - c * 9;
                lds[l * 2056 + c] = hv[j];
            }
        }
        __syncthreads();
        for (int l = 0; l < 9; ++l) {
            size_t row = (size_t)l * 256 + o;
            *(uint4*)(A + row * K_DIM + t * 8) = *(const uint4*)&lds[l * 2056 + t * 8];
        }
    } else if (b < 2313) {
        int l = b - 2304;
        size_t base = (size_t)l * 18432;    // conv_w[l][c][k], e = c*9+k
        for (int i = 0; i < 9; ++i) {
            int e0 = (t + i * 256) * 8;
            u16 hv[8];
            load8f(cw, base + e0, hv);
#pragma unroll
            for (int j = 0; j < 8; ++j) {
                int e = e0 + j;
                int c = e / 9, k = e - c * 9;
                lds[k * 2056 + c] = hv[j];
            }
        }
        __syncthreads();
        for (int k = 0; k < 9; ++k) {
            size_t row = 2304 + (size_t)k * 9 + l;
            *(uint4*)(A + row * K_DIM + t * 8) = *(const uint4*)&lds[k * 2056 + t * 8];
        }
    } else {
        // zero A rows 2385..2431 (rows 2432..2559 are garbage; each H row
        // depends only on its own A row and rows >=2432 are never stored;
        // garbage/valid rows never share an MFMA fragment since 2432%16==0)
        uint4 z = {0, 0, 0, 0};
        uint4* dst = (uint4*)(A + (size_t)2385 * K_DIM);
        for (int i = t; i < (47 * 2048) / 8; i += 256) dst[i] = z;
        if (t < 18) stats[t] = 0.0f;
    }
}

// ---------------- GEMM: H = A * XT^T (R16-validated, unchanged) ----------------
// 160x128 tile, BK=64, 4 waves (2Mx2N, per-wave 80x64), grid 16x32=512
// -> 2 independent blocks per CU (LDS 72KB/block, launch_bounds(256,2)).
__device__ __forceinline__ void gload_lds16(const void* g, void* l) {
    __builtin_amdgcn_global_load_lds((__attribute__((address_space(1))) void*)(g),
                                     (__attribute__((address_space(3))) void*)(l), 16, 0, 0);
}

#define STG_A(bb, kt) do {                                                                   \
    _Pragma("unroll") for (int j_ = 0; j_ < 5; ++j_) {                                       \
        int qd_ = w + 4 * j_;                                                                \
        gload_lds16(gA0 + (size_t)(qd_ * 8) * K_DIM + (size_t)(kt) * 64,                     \
                    As + (bb) * 10240 + qd_ * 512);                                          \
    }                                                                                        \
} while (0)

#define STG_B(bb, kt) do {                                                                   \
    _Pragma("unroll") for (int j_ = 0; j_ < 4; ++j_) {                                       \
        int qd_ = w + 4 * j_;                                                                \
        gload_lds16(gB0 + (size_t)(qd_ * 8) * K_DIM + (size_t)(kt) * 64,                     \
                    Bs + (bb) * 8192 + qd_ * 512);                                           \
    }                                                                                        \
} while (0)

#define RD_A(bb, mi, ks) (*(const short8*)(As + (bb) * 10240 + arow + (mi) * 1024 + col[ks]))
#define RD_B(bb, ni, ks) (*(const short8*)(Bs + (bb) * 8192 + brow + (ni) * 1024 + col[ks]))

#define MF(a, b, c) __builtin_amdgcn_mfma_f32_16x16x32_bf16(a, b, c, 0, 0, 0)

#define COMPUTE(par) do {                                                                    \
    bq[0][0] = RD_B(par, 0, 0); bq[1][0] = RD_B(par, 1, 0);                                  \
    bq[2][0] = RD_B(par, 2, 0); bq[3][0] = RD_B(par, 3, 0);                                  \
    aq[0][0] = RD_A(par, 0, 0); aq[1][0] = RD_A(par, 1, 0);                                  \
    aq[2][0] = RD_A(par, 2, 0); aq[3][0] = RD_A(par, 3, 0);                                  \
    aq[4][0] = RD_A(par, 4, 0);                                                              \
    bq[0][1] = RD_B(par, 0, 1); bq[1][1] = RD_B(par, 1, 1);                                  \
    bq[2][1] = RD_B(par, 2, 1); bq[3][1] = RD_B(par, 3, 1);                                  \
    aq[0][1] = RD_A(par, 0, 1); aq[1][1] = RD_A(par, 1, 1);                                  \
    aq[2][1] = RD_A(par, 2, 1); aq[3][1] = RD_A(par, 3, 1);                                  \
    aq[4][1] = RD_A(par, 4, 1);                                                              \
    __builtin_amdgcn_s_setprio(1);                                                           \
    _Pragma("unroll") for (int ks_ = 0; ks_ < 2; ++ks_)                                      \
      _Pragma("unroll") for (int mi_ = 0; mi_ < 5; ++mi_)                                    \
        _Pragma("unroll") for (int ni_ = 0; ni_ < 4; ++ni_)                                  \
          acc[mi_][ni_] = MF(aq[mi_][ks_], bq[ni_][ks_], acc[mi_][ni_]);                     \
    __builtin_amdgcn_s_setprio(0);                                                           \
} while (0)

#define FENCE() asm volatile("" ::: "memory")
#define BARRIER() do { FENCE(); __builtin_amdgcn_s_barrier(); FENCE(); } while (0)
#define VMW9() asm volatile("s_waitcnt vmcnt(9)" ::: "memory")
#define VMW0() asm volatile("s_waitcnt vmcnt(0)" ::: "memory")

__global__ __launch_bounds__(256, 2) void gemm_bt(const u16* __restrict__ A,
                                                  const u16* __restrict__ B,
                                                  __hip_bfloat16* __restrict__ C) {
    __shared__ __align__(16) u16 As[2 * 160 * 64];
    __shared__ __align__(16) u16 Bs[2 * 128 * 64];

    int orig = blockIdx.x;
    int wgid = (orig & 7) * 64 + (orig >> 3);
    int nt = wgid >> 4, mt = wgid & 15;    // nt 0..31, mt 0..15
    int m0 = mt * 160, n0 = nt * 128;

    int t = threadIdx.x;
    int w = t >> 6, L = t & 63;          // wave 0..3, lane
    int wm = w >> 1, wn = w & 1;         // wave grid 2M x 2N, per-wave 80x64
    int q = L >> 4, lm = L & 15;         // MFMA lane decomposition
    int lr = L >> 3, ls = L & 7;         // staging lane decomposition

    int csw = (ls ^ lr) * 8;
    const u16* gA0 = A + (size_t)(m0 + lr) * K_DIM + csw;
    const u16* gB0 = B + (size_t)(n0 + lr) * K_DIM + csw;

    int sw = (lm & 7) << 3;
    int arow = (wm * 80 + lm) * 64;
    int brow = (wn * 64 + lm) * 64;
    int col[2] = { (q * 8) ^ sw, (32 + q * 8) ^ sw };

    floatx4 acc[5][4];
    floatx4 z = {0.f, 0.f, 0.f, 0.f};
#pragma unroll
    for (int i = 0; i < 5; ++i)
#pragma unroll
        for (int j = 0; j < 4; ++j) acc[i][j] = z;

    short8 aq[5][2], bq[4][2];

    STG_A(0, 0); STG_B(0, 0);            // 9
    STG_B(1, 1); STG_A(1, 1);            // 9 -> 18 outstanding
    VMW9();                              // drain tile0 (A+B); keep tile1's 9
    BARRIER();

    for (int it = 0; it < 15; ++it) {
        int T = 2 * it;
        COMPUTE(0);                      // tile T from buf0
        BARRIER();
        STG_B(0, T + 2); STG_A(0, T + 2);   // 9 -> buf0
        VMW9();                          // drain tile T+1's 9; keep new 9
        BARRIER();
        COMPUTE(1);                      // tile T+1 from buf1
        BARRIER();
        if (it < 14) {
            STG_B(1, T + 3); STG_A(1, T + 3);  // 9 -> buf1
            VMW9();
            BARRIER();
        }
    }
    VMW0(); BARRIER();                   // tile 30 landed everywhere
    COMPUTE(0);                          // tile 30
    BARRIER();
    STG_B(1, 31); STG_A(1, 31);
    VMW0(); BARRIER();                   // tile 31 landed
    COMPUTE(1);                          // tile 31

    if (m0 + 159 < H_ROWS) {
#pragma unroll
        for (int mi = 0; mi < 5; ++mi) {
            int gm = m0 + wm * 80 + mi * 16 + q * 4;
#pragma unroll
            for (int ni = 0; ni < 4; ++ni) {
                int gn = n0 + wn * 64 + ni * 16 + lm;
#pragma unroll
                for (int r = 0; r < 4; ++r)
                    C[(size_t)(gm + r) * NPIX + gn] = __float2bfloat16(acc[mi][ni][r]);
            }
        }
    } else {
#pragma unroll
        for (int mi = 0; mi < 5; ++mi) {
            int gm = m0 + wm * 80 + mi * 16 + q * 4;
#pragma unroll
            for (int ni = 0; ni < 4; ++ni) {
                int gn = n0 + wn * 64 + ni * 16 + lm;
#pragma unroll
                for (int r = 0; r < 4; ++r) {
                    int row = gm + r;
                    if (row < H_ROWS)
                        C[(size_t)row * NPIX + gn] = __float2bfloat16(acc[mi][ni][r]);
                }
            }
        }
    }
}

// ---------------- sigma_raw + BN stats; R17: shfl-xor wave reduce (no LDS tree) ----------------
__global__ void sigma_stats(const __hip_bfloat16* __restrict__ Hm, float* __restrict__ sraw,
                            float* __restrict__ stats) {
    int b = blockIdx.x;           // (n*9 + l)*4 + quarter
    int qq = b & 3, nl = b >> 2;
    int n = nl / 9, l = nl - n * 9;
    int t = threadIdx.x;
    int pix = qq * 256 + t;
    int y = pix >> 5, x = pix & 31;
    float v = 0.f;
#pragma unroll
    for (int k = 0; k < 9; ++k) {
        int yy = y + k / 3 - 1, xx = x + (k % 3) - 1;
        if (yy >= 0 && yy < 32 && xx >= 0 && xx < 32)
            v += __bfloat162float(Hm[(size_t)(2304 + k * 9 + l) * NPIX + n * HW + yy * 32 + xx]);
    }
    sraw[(size_t)nl * HW + pix] = v;
    float s1 = v, s2 = v * v;
#pragma unroll
    for (int off = 32; off > 0; off >>= 1) {
        s1 += __shfl_xor(s1, off);
        s2 += __shfl_xor(s2, off);
    }
    if ((t & 63) == 0) { atomicAdd(&stats[l], s1); atomicAdd(&stats[9 + l], s2); }
}

// ---------------- tail v4: 4 pixels/thread, vectorized sraw(float4)/H(uint2 windows)/out(float4) ----------------
// grid 512: b = n*128 + og; channels o = 2*og, 2*og+1; pixels t*4 .. t*4+3 (same image row)
__global__ void tail(const __hip_bfloat16* __restrict__ Hm, const float* __restrict__ sraw,
                     const float* __restrict__ stats, const float* __restrict__ gamma,
                     const float* __restrict__ beta, float* __restrict__ out) {
    int b = blockIdx.x;
    int n = b >> 7, og = b & 127;
    int t = threadIdx.x;
    int pix0 = t << 2;
    // fold BN into scale/shift: tv = sraw*sc + sb
    float sc[9], sb[9];
#pragma unroll
    for (int l = 0; l < 9; ++l) {
        float m = stats[l] * (1.f / 4096.f);
        float var = stats[9 + l] * (1.f / 4096.f) - m * m;
        float is = rsqrtf(var + BN_EPS);
        float g = gamma[l];
        sc[l] = is * g;
        sb[l] = beta[l] - m * is * g;
    }
    const __hip_bfloat16* hb = Hm + (size_t)(og * 2) * NPIX + (size_t)n * HW;
    float* ob = out + ((size_t)n * 256 + og * 2) * HW;
    int y = pix0 >> 5, x0 = pix0 & 31;

    float v[9][4];
    float mx[4] = {-1e30f, -1e30f, -1e30f, -1e30f};
#pragma unroll
    for (int l = 0; l < 9; ++l) {
        float4 sr = *(const float4*)(sraw + (size_t)(n * 9 + l) * HW + pix0);
        float f0 = sr.x * sc[l] + sb[l];
        float f1 = sr.y * sc[l] + sb[l];
        float f2 = sr.z * sc[l] + sb[l];
        float f3 = sr.w * sc[l] + sb[l];
        v[l][0] = f0; v[l][1] = f1; v[l][2] = f2; v[l][3] = f3;
        mx[0] = fmaxf(mx[0], f0); mx[1] = fmaxf(mx[1], f1);
        mx[2] = fmaxf(mx[2], f2); mx[3] = fmaxf(mx[3], f3);
    }
    float ssum[4] = {0.f, 0.f, 0.f, 0.f};
#pragma unroll
    for (int l = 0; l < 9; ++l)
#pragma unroll
        for (int j = 0; j < 4; ++j) {
            v[l][j] = __expf(v[l][j] - mx[j]);
            ssum[j] += v[l][j];
        }
    float inv[4];
#pragma unroll
    for (int j = 0; j < 4; ++j) inv[j] = 1.f / ssum[j];

    float a0c[4] = {0.f, 0.f, 0.f, 0.f}, a1c[4] = {0.f, 0.f, 0.f, 0.f};
#pragma unroll
    for (int l = 0; l < 9; ++l) {
        const int dy = l / 3 - 1, dx = l % 3 - 1;
        const int off = dy * 32 + dx;
        int yy = y + dy;
        bool yok = (yy >= 0) && (yy < 32);
        int a = pix0 + off;
        int ab = a & ~3;                 // 8B-aligned window start; a-ab == dx&3
        const __hip_bfloat16* hrow = hb + (size_t)(l * 256) * NPIX;
        u16 w0[8], w1[8];
        *(uint2*)&w0[0] = *(const uint2*)(hrow + ab);
        *(uint2*)&w0[4] = *(const uint2*)(hrow + ab + 4);
        *(uint2*)&w1[0] = *(const uint2*)(hrow + NPIX + ab);
        *(uint2*)&w1[4] = *(const uint2*)(hrow + NPIX + ab + 4);
        const int sh = dx & 3;           // compile-time per l
#pragma unroll
        for (int j = 0; j < 4; ++j) {
            bool ok = yok;
            if (dx < 0) ok = ok && (x0 + j > 0);
            if (dx > 0) ok = ok && (x0 + j < 31);
            float sv = v[l][j] * inv[j];
            float h0 = ok ? b2f(w0[sh + j]) : 0.f;   // mask BEFORE multiply (garbage may be NaN)
            float h1 = ok ? b2f(w1[sh + j]) : 0.f;
            a0c[j] += sv * h0;
            a1c[j] += sv * h1;
        }
    }
    float4 o0 = {a0c[0], a0c[1], a0c[2], a0c[3]};
    float4 o1 = {a1c[0], a1c[1], a1c[2], a1c[3]};
    *(float4*)(ob + pix0) = o0;
    *(float4*)(ob + HW + pix0) = o1;
}

extern "C" void kernel_launch(void* const* d_in, const int* in_sizes, int n_in,
                              void* d_out, int out_size, void* d_ws, size_t ws_size,
                              hipStream_t stream) {
    const float* x     = (const float*)d_in[0];
    const float* cw    = (const float*)d_in[1];
    const float* gamma = (const float*)d_in[2];
    const float* beta  = (const float*)d_in[3];
    const float* wgt   = (const float*)d_in[4];

    char* ws = (char*)d_ws;
    u16*   Abuf = (u16*)(ws + OFF_A);
    u16*   XT   = (u16*)(ws + OFF_XT);
    u16*   Hm   = (u16*)(ws + OFF_H);
    float* sraw = (float*)(ws + OFF_SRAW);
    float* stats= (float*)(ws + OFF_STAT);

    build_all<<<2314, 256, 0, stream>>>(x, wgt, cw, XT, Abuf, stats);
    gemm_bt<<<512, 256, 0, stream>>>(Abuf, XT, (__hip_bfloat16*)Hm);
    sigma_stats<<<N_IMG * KK * 4, 256, 0, stream>>>((const __hip_bfloat16*)Hm, sraw, stats);
    tail<<<512, 256, 0, stream>>>((const __hip_bfloat16*)Hm, sraw, stats, gamma, beta, (float*)d_out);
}

// Round 8
// 161.517 us; speedup vs baseline: 1.0107x; 1.0107x over previous
//
#include <hip/hip_runtime.h>
#include <hip/hip_bf16.h>
#include <stdint.h>

typedef unsigned short u16;
typedef __attribute__((ext_vector_type(8))) short short8;
typedef __attribute__((ext_vector_type(4))) float floatx4;

#define N_IMG 4
#define C_IN  2048
#define HW    1024
#define KK    9
#define O_OUT 256
#define NPIX  4096          // N_IMG*HW
#define M_PAD  2560         // 16 M-tiles x 160 rows (2304 proj + 81 conv + pad)
#define H_ROWS 2432         // H rows actually stored (proj 2304 + conv 81 + pad)
#define K_DIM  2048
#define BN_EPS 1e-5f

// workspace offsets (bytes), 256-aligned
#define OFF_A    0u                // A: 2560*2048*2 = 10485760
#define OFF_XT   10485760u         // XT: 4096*2048*2 = 16777216
#define OFF_H    27262976u         // H: 2432*4096*2 = 19922944
#define OFF_SRAW 47185920u         // sraw: 36864*4
#define OFF_STAT 47333376u

// fp32 -> bf16 bits, round-to-nearest-even
__device__ __forceinline__ u16 f2b(float f) {
    unsigned u = __float_as_uint(f);
    return (u16)((u + 0x7FFFu + ((u >> 16) & 1u)) >> 16);
}

__device__ __forceinline__ float b2f(u16 h) {
    return __uint_as_float((unsigned)h << 16);
}

__device__ __forceinline__ void load8f(const float* base, size_t eidx, u16* out) {
    const float* p = base + eidx;
    float4 a = ((const float4*)p)[0];
    float4 b = ((const float4*)p)[1];
    float f[8] = {a.x, a.y, a.z, a.w, b.x, b.y, b.z, b.w};
#pragma unroll
    for (int j = 0; j < 8; ++j) out[j] = f2b(f[j]);
}

// ---------------- merged staging kernel (R10-validated, unchanged) ----------------
__global__ void build_all(const float* __restrict__ x, const float* __restrict__ wgt,
                          const float* __restrict__ cw, u16* __restrict__ xt,
                          u16* __restrict__ A, float* __restrict__ stats) {
    __shared__ __align__(16) u16 lds[9 * 2056];
    int b = blockIdx.x, t = threadIdx.x;
    if (b < 2048) {
        int c0 = (b & 31) * 64, p0 = ((b >> 5) & 15) * 64, n = b >> 9;
        int rp = t >> 3;                // channel-pair 0..31
        int pv = (t & 7) * 8;           // pixel group
        u16 h0[8], h1[8];
        load8f(x, (size_t)(n * C_IN + c0 + 2 * rp) * HW + p0 + pv, h0);
        load8f(x, (size_t)(n * C_IN + c0 + 2 * rp + 1) * HW + p0 + pv, h1);
        unsigned* l32 = (unsigned*)lds;   // [64 pixels][stride 35 u32]
#pragma unroll
        for (int j = 0; j < 8; ++j)
            l32[(pv + j) * 35 + rp] = (unsigned)h0[j] | ((unsigned)h1[j] << 16);
        __syncthreads();
        int pr = t >> 3, cq = (t & 7) * 4;   // pixel, u32-quad (8 channels)
        unsigned o0[4], o1[4];
#pragma unroll
        for (int i = 0; i < 4; ++i) {
            o0[i] = l32[pr * 35 + cq + i];
            o1[i] = l32[(pr + 32) * 35 + cq + i];
        }
        *(uint4*)(xt + (size_t)(n * HW + p0 + pr) * K_DIM + c0 + cq * 2) = *(uint4*)o0;
        *(uint4*)(xt + (size_t)(n * HW + p0 + pr + 32) * K_DIM + c0 + cq * 2) = *(uint4*)o1;
    } else if (b < 2304) {
        int o = b - 2048;
        size_t base = (size_t)o * 18432;   // weight[o][c][l], e = c*9+l
        for (int i = 0; i < 9; ++i) {
            int e0 = (t + i * 256) * 8;
            u16 hv[8];
            load8f(wgt, base + e0, hv);
#pragma unroll
            for (int j = 0; j < 8; ++j) {
                int e = e0 + j;
                int c = e / 9, l = e - c * 9;
                lds[l * 2056 + c] = hv[j];
            }
        }
        __syncthreads();
        for (int l = 0; l < 9; ++l) {
            size_t row = (size_t)l * 256 + o;
            *(uint4*)(A + row * K_DIM + t * 8) = *(const uint4*)&lds[l * 2056 + t * 8];
        }
    } else if (b < 2313) {
        int l = b - 2304;
        size_t base = (size_t)l * 18432;    // conv_w[l][c][k], e = c*9+k
        for (int i = 0; i < 9; ++i) {
            int e0 = (t + i * 256) * 8;
            u16 hv[8];
            load8f(cw, base + e0, hv);
#pragma unroll
            for (int j = 0; j < 8; ++j) {
                int e = e0 + j;
                int c = e / 9, k = e - c * 9;
                lds[k * 2056 + c] = hv[j];
            }
        }
        __syncthreads();
        for (int k = 0; k < 9; ++k) {
            size_t row = 2304 + (size_t)k * 9 + l;
            *(uint4*)(A + row * K_DIM + t * 8) = *(const uint4*)&lds[k * 2056 + t * 8];
        }
    } else {
        // zero A rows 2385..2431 (rows 2432..2559 are garbage; each H row
        // depends only on its own A row and rows >=2432 are never stored;
        // garbage/valid rows never share an MFMA fragment since 2432%16==0)
        uint4 z = {0, 0, 0, 0};
        uint4* dst = (uint4*)(A + (size_t)2385 * K_DIM);
        for (int i = t; i < (47 * 2048) / 8; i += 256) dst[i] = z;
        if (t < 18) stats[t] = 0.0f;
    }
}

// ---------------- GEMM: H = A * XT^T (R16-validated, unchanged) ----------------
// 160x128 tile, BK=64, 4 waves (2Mx2N, per-wave 80x64), grid 16x32=512
// -> 2 independent blocks per CU (LDS 72KB/block, launch_bounds(256,2)).
__device__ __forceinline__ void gload_lds16(const void* g, void* l) {
    __builtin_amdgcn_global_load_lds((__attribute__((address_space(1))) void*)(g),
                                     (__attribute__((address_space(3))) void*)(l), 16, 0, 0);
}

#define STG_A(bb, kt) do {                                                                   \
    _Pragma("unroll") for (int j_ = 0; j_ < 5; ++j_) {                                       \
        int qd_ = w + 4 * j_;                                                                \
        gload_lds16(gA0 + (size_t)(qd_ * 8) * K_DIM + (size_t)(kt) * 64,                     \
                    As + (bb) * 10240 + qd_ * 512);                                          \
    }                                                                                        \
} while (0)

#define STG_B(bb, kt) do {                                                                   \
    _Pragma("unroll") for (int j_ = 0; j_ < 4; ++j_) {                                       \
        int qd_ = w + 4 * j_;                                                                \
        gload_lds16(gB0 + (size_t)(qd_ * 8) * K_DIM + (size_t)(kt) * 64,                     \
                    Bs + (bb) * 8192 + qd_ * 512);                                           \
    }                                                                                        \
} while (0)

#define RD_A(bb, mi, ks) (*(const short8*)(As + (bb) * 10240 + arow + (mi) * 1024 + col[ks]))
#define RD_B(bb, ni, ks) (*(const short8*)(Bs + (bb) * 8192 + brow + (ni) * 1024 + col[ks]))

#define MF(a, b, c) __builtin_amdgcn_mfma_f32_16x16x32_bf16(a, b, c, 0, 0, 0)

#define COMPUTE(par) do {                                                                    \
    bq[0][0] = RD_B(par, 0, 0); bq[1][0] = RD_B(par, 1, 0);                                  \
    bq[2][0] = RD_B(par, 2, 0); bq[3][0] = RD_B(par, 3, 0);                                  \
    aq[0][0] = RD_A(par, 0, 0); aq[1][0] = RD_A(par, 1, 0);                                  \
    aq[2][0] = RD_A(par, 2, 0); aq[3][0] = RD_A(par, 3, 0);                                  \
    aq[4][0] = RD_A(par, 4, 0);                                                              \
    bq[0][1] = RD_B(par, 0, 1); bq[1][1] = RD_B(par, 1, 1);                                  \
    bq[2][1] = RD_B(par, 2, 1); bq[3][1] = RD_B(par, 3, 1);                                  \
    aq[0][1] = RD_A(par, 0, 1); aq[1][1] = RD_A(par, 1, 1);                                  \
    aq[2][1] = RD_A(par, 2, 1); aq[3][1] = RD_A(par, 3, 1);                                  \
    aq[4][1] = RD_A(par, 4, 1);                                                              \
    __builtin_amdgcn_s_setprio(1);                                                           \
    _Pragma("unroll") for (int ks_ = 0; ks_ < 2; ++ks_)                                      \
      _Pragma("unroll") for (int mi_ = 0; mi_ < 5; ++mi_)                                    \
        _Pragma("unroll") for (int ni_ = 0; ni_ < 4; ++ni_)                                  \
          acc[mi_][ni_] = MF(aq[mi_][ks_], bq[ni_][ks_], acc[mi_][ni_]);                     \
    __builtin_amdgcn_s_setprio(0);                                                           \
} while (0)

#define FENCE() asm volatile("" ::: "memory")
#define BARRIER() do { FENCE(); __builtin_amdgcn_s_barrier(); FENCE(); } while (0)
#define VMW9() asm volatile("s_waitcnt vmcnt(9)" ::: "memory")
#define VMW0() asm volatile("s_waitcnt vmcnt(0)" ::: "memory")

__global__ __launch_bounds__(256, 2) void gemm_bt(const u16* __restrict__ A,
                                                  const u16* __restrict__ B,
                                                  __hip_bfloat16* __restrict__ C) {
    __shared__ __align__(16) u16 As[2 * 160 * 64];
    __shared__ __align__(16) u16 Bs[2 * 128 * 64];

    int orig = blockIdx.x;
    int wgid = (orig & 7) * 64 + (orig >> 3);
    int nt = wgid >> 4, mt = wgid & 15;    // nt 0..31, mt 0..15
    int m0 = mt * 160, n0 = nt * 128;

    int t = threadIdx.x;
    int w = t >> 6, L = t & 63;          // wave 0..3, lane
    int wm = w >> 1, wn = w & 1;         // wave grid 2M x 2N, per-wave 80x64
    int q = L >> 4, lm = L & 15;         // MFMA lane decomposition
    int lr = L >> 3, ls = L & 7;         // staging lane decomposition

    int csw = (ls ^ lr) * 8;
    const u16* gA0 = A + (size_t)(m0 + lr) * K_DIM + csw;
    const u16* gB0 = B + (size_t)(n0 + lr) * K_DIM + csw;

    int sw = (lm & 7) << 3;
    int arow = (wm * 80 + lm) * 64;
    int brow = (wn * 64 + lm) * 64;
    int col[2] = { (q * 8) ^ sw, (32 + q * 8) ^ sw };

    floatx4 acc[5][4];
    floatx4 z = {0.f, 0.f, 0.f, 0.f};
#pragma unroll
    for (int i = 0; i < 5; ++i)
#pragma unroll
        for (int j = 0; j < 4; ++j) acc[i][j] = z;

    short8 aq[5][2], bq[4][2];

    STG_A(0, 0); STG_B(0, 0);            // 9
    STG_B(1, 1); STG_A(1, 1);            // 9 -> 18 outstanding
    VMW9();                              // drain tile0 (A+B); keep tile1's 9
    BARRIER();

    for (int it = 0; it < 15; ++it) {
        int T = 2 * it;
        COMPUTE(0);                      // tile T from buf0
        BARRIER();
        STG_B(0, T + 2); STG_A(0, T + 2);   // 9 -> buf0
        VMW9();                          // drain tile T+1's 9; keep new 9
        BARRIER();
        COMPUTE(1);                      // tile T+1 from buf1
        BARRIER();
        if (it < 14) {
            STG_B(1, T + 3); STG_A(1, T + 3);  // 9 -> buf1
            VMW9();
            BARRIER();
        }
    }
    VMW0(); BARRIER();                   // tile 30 landed everywhere
    COMPUTE(0);                          // tile 30
    BARRIER();
    STG_B(1, 31); STG_A(1, 31);
    VMW0(); BARRIER();                   // tile 31 landed
    COMPUTE(1);                          // tile 31

    if (m0 + 159 < H_ROWS) {
#pragma unroll
        for (int mi = 0; mi < 5; ++mi) {
            int gm = m0 + wm * 80 + mi * 16 + q * 4;
#pragma unroll
            for (int ni = 0; ni < 4; ++ni) {
                int gn = n0 + wn * 64 + ni * 16 + lm;
#pragma unroll
                for (int r = 0; r < 4; ++r)
                    C[(size_t)(gm + r) * NPIX + gn] = __float2bfloat16(acc[mi][ni][r]);
            }
        }
    } else {
#pragma unroll
        for (int mi = 0; mi < 5; ++mi) {
            int gm = m0 + wm * 80 + mi * 16 + q * 4;
#pragma unroll
            for (int ni = 0; ni < 4; ++ni) {
                int gn = n0 + wn * 64 + ni * 16 + lm;
#pragma unroll
                for (int r = 0; r < 4; ++r) {
                    int row = gm + r;
                    if (row < H_ROWS)
                        C[(size_t)row * NPIX + gn] = __float2bfloat16(acc[mi][ni][r]);
                }
            }
        }
    }
}

// ---------------- sigma_raw + BN stats (R17 shfl-xor wave reduce, kept) ----------------
__global__ void sigma_stats(const __hip_bfloat16* __restrict__ Hm, float* __restrict__ sraw,
                            float* __restrict__ stats) {
    int b = blockIdx.x;           // (n*9 + l)*4 + quarter
    int qq = b & 3, nl = b >> 2;
    int n = nl / 9, l = nl - n * 9;
    int t = threadIdx.x;
    int pix = qq * 256 + t;
    int y = pix >> 5, x = pix & 31;
    float v = 0.f;
#pragma unroll
    for (int k = 0; k < 9; ++k) {
        int yy = y + k / 3 - 1, xx = x + (k % 3) - 1;
        if (yy >= 0 && yy < 32 && xx >= 0 && xx < 32)
            v += __bfloat162float(Hm[(size_t)(2304 + k * 9 + l) * NPIX + n * HW + yy * 32 + xx]);
    }
    sraw[(size_t)nl * HW + pix] = v;
    float s1 = v, s2 = v * v;
#pragma unroll
    for (int off = 32; off > 0; off >>= 1) {
        s1 += __shfl_xor(s1, off);
        s2 += __shfl_xor(s2, off);
    }
    if ((t & 63) == 0) { atomicAdd(&stats[l], s1); atomicAdd(&stats[9 + l], s2); }
}

// ---------------- tail v5: 4 px/thread, ONE channel/block -> 1024 blocks (v3's TLP, v4's vectorization) ----------------
// grid 1024: b = n*256 + o; pixels t*4 .. t*4+3 of image n, output channel o
__global__ void tail(const __hip_bfloat16* __restrict__ Hm, const float* __restrict__ sraw,
                     const float* __restrict__ stats, const float* __restrict__ gamma,
                     const float* __restrict__ beta, float* __restrict__ out) {
    int b = blockIdx.x;
    int n = b >> 8, o = b & 255;
    int t = threadIdx.x;
    int pix0 = t << 2;
    // fold BN into scale/shift: tv = sraw*sc + sb
    float sc[9], sb[9];
#pragma unroll
    for (int l = 0; l < 9; ++l) {
        float m = stats[l] * (1.f / 4096.f);
        float var = stats[9 + l] * (1.f / 4096.f) - m * m;
        float is = rsqrtf(var + BN_EPS);
        float g = gamma[l];
        sc[l] = is * g;
        sb[l] = beta[l] - m * is * g;
    }
    const __hip_bfloat16* hb = Hm + (size_t)o * NPIX + (size_t)n * HW;
    float* ob = out + ((size_t)n * 256 + o) * HW;
    int y = pix0 >> 5, x0 = pix0 & 31;

    float v[9][4];
    float mx[4] = {-1e30f, -1e30f, -1e30f, -1e30f};
#pragma unroll
    for (int l = 0; l < 9; ++l) {
        float4 sr = *(const float4*)(sraw + (size_t)(n * 9 + l) * HW + pix0);
        float f0 = sr.x * sc[l] + sb[l];
        float f1 = sr.y * sc[l] + sb[l];
        float f2 = sr.z * sc[l] + sb[l];
        float f3 = sr.w * sc[l] + sb[l];
        v[l][0] = f0; v[l][1] = f1; v[l][2] = f2; v[l][3] = f3;
        mx[0] = fmaxf(mx[0], f0); mx[1] = fmaxf(mx[1], f1);
        mx[2] = fmaxf(mx[2], f2); mx[3] = fmaxf(mx[3], f3);
    }
    float ssum[4] = {0.f, 0.f, 0.f, 0.f};
#pragma unroll
    for (int l = 0; l < 9; ++l)
#pragma unroll
        for (int j = 0; j < 4; ++j) {
            v[l][j] = __expf(v[l][j] - mx[j]);
            ssum[j] += v[l][j];
        }
    float inv[4];
#pragma unroll
    for (int j = 0; j < 4; ++j) inv[j] = 1.f / ssum[j];

    float a0c[4] = {0.f, 0.f, 0.f, 0.f};
#pragma unroll
    for (int l = 0; l < 9; ++l) {
        const int dy = l / 3 - 1, dx = l % 3 - 1;
        const int off = dy * 32 + dx;
        int yy = y + dy;
        bool yok = (yy >= 0) && (yy < 32);
        int a = pix0 + off;
        int ab = a & ~3;                 // 8B-aligned window start; a-ab == dx&3 (pix0,dy*32 are mult of 4)
        const __hip_bfloat16* hrow = hb + (size_t)(l * 256) * NPIX;
        u16 w0[8];
        *(uint2*)&w0[0] = *(const uint2*)(hrow + ab);
        *(uint2*)&w0[4] = *(const uint2*)(hrow + ab + 4);
        const int sh = dx & 3;           // compile-time per l
#pragma unroll
        for (int j = 0; j < 4; ++j) {
            bool ok = yok;
            if (dx < 0) ok = ok && (x0 + j > 0);
            if (dx > 0) ok = ok && (x0 + j < 31);
            float sv = v[l][j] * inv[j];
            float h0 = ok ? b2f(w0[sh + j]) : 0.f;   // mask BEFORE multiply (garbage may be NaN)
            a0c[j] += sv * h0;
        }
    }
    float4 o0 = {a0c[0], a0c[1], a0c[2], a0c[3]};
    *(float4*)(ob + pix0) = o0;
}

extern "C" void kernel_launch(void* const* d_in, const int* in_sizes, int n_in,
                              void* d_out, int out_size, void* d_ws, size_t ws_size,
                              hipStream_t stream) {
    const float* x     = (const float*)d_in[0];
    const float* cw    = (const float*)d_in[1];
    const float* gamma = (const float*)d_in[2];
    const float* beta  = (const float*)d_in[3];
    const float* wgt   = (const float*)d_in[4];

    char* ws = (char*)d_ws;
    u16*   Abuf = (u16*)(ws + OFF_A);
    u16*   XT   = (u16*)(ws + OFF_XT);
    u16*   Hm   = (u16*)(ws + OFF_H);
    float* sraw = (float*)(ws + OFF_SRAW);
    float* stats= (float*)(ws + OFF_STAT);

    build_all<<<2314, 256, 0, stream>>>(x, wgt, cw, XT, Abuf, stats);
    gemm_bt<<<512, 256, 0, stream>>>(Abuf, XT, (__hip_bfloat16*)Hm);
    sigma_stats<<<N_IMG * KK * 4, 256, 0, stream>>>((const __hip_bfloat16*)Hm, sraw, stats);
    tail<<<1024, 256, 0, stream>>>((const __hip_bfloat16*)Hm, sraw, stats, gamma, beta, (float*)d_out);
}

// Round 9
// 157.230 us; speedup vs baseline: 1.0382x; 1.0273x over previous
//
#include <hip/hip_runtime.h>
#include <hip/hip_bf16.h>
#include <stdint.h>

typedef unsigned short u16;
typedef __attribute__((ext_vector_type(8))) short short8;
typedef __attribute__((ext_vector_type(4))) float floatx4;

#define N_IMG 4
#define C_IN  2048
#define HW    1024
#define KK    9
#define O_OUT 256
#define NPIX  4096          // N_IMG*HW
#define M_PAD  2560         // 16 M-tiles x 160 rows (2304 proj + 81 conv + pad)
#define H_ROWS 2432         // H rows actually stored (proj 2304 + conv 81 + pad)
#define K_DIM  2048
#define BN_EPS 1e-5f

// workspace offsets (bytes), 256-aligned
#define OFF_A    0u                // A: 2560*2048*2 = 10485760
#define OFF_XT   10485760u         // XT: 4096*2048*2 = 16777216
#define OFF_H    27262976u         // H: 2432*4096*2 = 19922944
#define OFF_SRAW 47185920u         // sraw: 36864*4
#define OFF_STAT 47333376u

// fp32 -> bf16 bits, round-to-nearest-even
__device__ __forceinline__ u16 f2b(float f) {
    unsigned u = __float_as_uint(f);
    return (u16)((u + 0x7FFFu + ((u >> 16) & 1u)) >> 16);
}

__device__ __forceinline__ void load8f(const float* base, size_t eidx, u16* out) {
    const float* p = base + eidx;
    float4 a = ((const float4*)p)[0];
    float4 b = ((const float4*)p)[1];
    float f[8] = {a.x, a.y, a.z, a.w, b.x, b.y, b.z, b.w};
#pragma unroll
    for (int j = 0; j < 8; ++j) out[j] = f2b(f[j]);
}

// ---------------- merged staging kernel (R10-validated, unchanged) ----------------
__global__ void build_all(const float* __restrict__ x, const float* __restrict__ wgt,
                          const float* __restrict__ cw, u16* __restrict__ xt,
                          u16* __restrict__ A, float* __restrict__ stats) {
    __shared__ __align__(16) u16 lds[9 * 2056];
    int b = blockIdx.x, t = threadIdx.x;
    if (b < 2048) {
        int c0 = (b & 31) * 64, p0 = ((b >> 5) & 15) * 64, n = b >> 9;
        int rp = t >> 3;                // channel-pair 0..31
        int pv = (t & 7) * 8;           // pixel group
        u16 h0[8], h1[8];
        load8f(x, (size_t)(n * C_IN + c0 + 2 * rp) * HW + p0 + pv, h0);
        load8f(x, (size_t)(n * C_IN + c0 + 2 * rp + 1) * HW + p0 + pv, h1);
        unsigned* l32 = (unsigned*)lds;   // [64 pixels][stride 35 u32]
#pragma unroll
        for (int j = 0; j < 8; ++j)
            l32[(pv + j) * 35 + rp] = (unsigned)h0[j] | ((unsigned)h1[j] << 16);
        __syncthreads();
        int pr = t >> 3, cq = (t & 7) * 4;   // pixel, u32-quad (8 channels)
        unsigned o0[4], o1[4];
#pragma unroll
        for (int i = 0; i < 4; ++i) {
            o0[i] = l32[pr * 35 + cq + i];
            o1[i] = l32[(pr + 32) * 35 + cq + i];
        }
        *(uint4*)(xt + (size_t)(n * HW + p0 + pr) * K_DIM + c0 + cq * 2) = *(uint4*)o0;
        *(uint4*)(xt + (size_t)(n * HW + p0 + pr + 32) * K_DIM + c0 + cq * 2) = *(uint4*)o1;
    } else if (b < 2304) {
        int o = b - 2048;
        size_t base = (size_t)o * 18432;   // weight[o][c][l], e = c*9+l
        for (int i = 0; i < 9; ++i) {
            int e0 = (t + i * 256) * 8;
            u16 hv[8];
            load8f(wgt, base + e0, hv);
#pragma unroll
            for (int j = 0; j < 8; ++j) {
                int e = e0 + j;
                int c = e / 9, l = e - c * 9;
                lds[l * 2056 + c] = hv[j];
            }
        }
        __syncthreads();
        for (int l = 0; l < 9; ++l) {
            size_t row = (size_t)l * 256 + o;
            *(uint4*)(A + row * K_DIM + t * 8) = *(const uint4*)&lds[l * 2056 + t * 8];
        }
    } else if (b < 2313) {
        int l = b - 2304;
        size_t base = (size_t)l * 18432;    // conv_w[l][c][k], e = c*9+k
        for (int i = 0; i < 9; ++i) {
            int e0 = (t + i * 256) * 8;
            u16 hv[8];
            load8f(cw, base + e0, hv);
#pragma unroll
            for (int j = 0; j < 8; ++j) {
                int e = e0 + j;
                int c = e / 9, k = e - c * 9;
                lds[k * 2056 + c] = hv[j];
            }
        }
        __syncthreads();
        for (int k = 0; k < 9; ++k) {
            size_t row = 2304 + (size_t)k * 9 + l;
            *(uint4*)(A + row * K_DIM + t * 8) = *(const uint4*)&lds[k * 2056 + t * 8];
        }
    } else {
        // zero A rows 2385..2431 (rows 2432..2559 are garbage; each H row
        // depends only on its own A row and rows >=2432 are never stored;
        // garbage/valid rows never share an MFMA fragment since 2432%16==0)
        uint4 z = {0, 0, 0, 0};
        uint4* dst = (uint4*)(A + (size_t)2385 * K_DIM);
        for (int i = t; i < (47 * 2048) / 8; i += 256) dst[i] = z;
        if (t < 18) stats[t] = 0.0f;
    }
}

// ---------------- GEMM: H = A * XT^T ----------------
// R18: R6 substrate (160x128 tile, BK=64, 4 waves 2Mx2N, grid 512, 2 blocks/CU)
// + 3-phase register prefetch per K-tile: operand sets s0(A01,B01; double-
// parity), s1(A23,B23), s2(A4). Cross-tile s0 prefetch removes the post-
// barrier first-read latency window (~150-200cy/tile that the compiler's
// in-stream lgkm waits cannot hide across a barrier). Hazard ledger:
// explicit lgkmcnt(0) before BARRIER_a (reads drained before restage);
// per-wave VMW before BARRIER_b (staged data published before prefetch).
__device__ __forceinline__ void gload_lds16(const void* g, void* l) {
    __builtin_amdgcn_global_load_lds((__attribute__((address_space(1))) void*)(g),
                                     (__attribute__((address_space(3))) void*)(l), 16, 0, 0);
}

#define STG_A(bb, kt) do {                                                                   \
    _Pragma("unroll") for (int j_ = 0; j_ < 5; ++j_) {                                       \
        int qd_ = w + 4 * j_;                                                                \
        gload_lds16(gA0 + (size_t)(qd_ * 8) * K_DIM + (size_t)(kt) * 64,                     \
                    As + (bb) * 10240 + qd_ * 512);                                          \
    }                                                                                        \
} while (0)

#define STG_B(bb, kt) do {                                                                   \
    _Pragma("unroll") for (int j_ = 0; j_ < 4; ++j_) {                                       \
        int qd_ = w + 4 * j_;                                                                \
        gload_lds16(gB0 + (size_t)(qd_ * 8) * K_DIM + (size_t)(kt) * 64,                     \
                    Bs + (bb) * 8192 + qd_ * 512);                                           \
    }                                                                                        \
} while (0)

#define RD_A(bb, mi, ks) (*(const short8*)(As + (bb) * 10240 + arow + (mi) * 1024 + col[ks]))
#define RD_B(bb, ni, ks) (*(const short8*)(Bs + (bb) * 8192 + brow + (ni) * 1024 + col[ks]))

#define MF(a, b, c) __builtin_amdgcn_mfma_f32_16x16x32_bf16(a, b, c, 0, 0, 0)

// prefetch reads (buffer index == tile parity for s0)
#define PRE_S0(par) do {                                                     \
    s0A[par][0][0] = RD_A(par, 0, 0); s0A[par][1][0] = RD_A(par, 1, 0);      \
    s0B[par][0][0] = RD_B(par, 0, 0); s0B[par][1][0] = RD_B(par, 1, 0);      \
    s0A[par][0][1] = RD_A(par, 0, 1); s0A[par][1][1] = RD_A(par, 1, 1);      \
    s0B[par][0][1] = RD_B(par, 0, 1); s0B[par][1][1] = RD_B(par, 1, 1);      \
} while (0)

#define PRE_S1(par) do {                                                     \
    s1A[0][0] = RD_A(par, 2, 0); s1A[1][0] = RD_A(par, 3, 0);                \
    s1B[0][0] = RD_B(par, 2, 0); s1B[1][0] = RD_B(par, 3, 0);                \
    s1A[0][1] = RD_A(par, 2, 1); s1A[1][1] = RD_A(par, 3, 1);                \
    s1B[0][1] = RD_B(par, 2, 1); s1B[1][1] = RD_B(par, 3, 1);                \
} while (0)

#define PRE_S2(par) do { s2A[0] = RD_A(par, 4, 0); s2A[1] = RD_A(par, 4, 1); } while (0)

// MFMA groups: G0 = mi01 x ni01 (8); G1 = cross terms (16); G2 = mi23 x ni23 + mi4 x all (16)
#define G0K(par, k) do {                                                     \
    acc[0][0] = MF(s0A[par][0][k], s0B[par][0][k], acc[0][0]);               \
    acc[0][1] = MF(s0A[par][0][k], s0B[par][1][k], acc[0][1]);               \
    acc[1][0] = MF(s0A[par][1][k], s0B[par][0][k], acc[1][0]);               \
    acc[1][1] = MF(s0A[par][1][k], s0B[par][1][k], acc[1][1]);               \
} while (0)
#define G0(par) do { G0K(par, 0); G0K(par, 1); } while (0)

#define G1K(par, k) do {                                                     \
    acc[0][2] = MF(s0A[par][0][k], s1B[0][k], acc[0][2]);                    \
    acc[0][3] = MF(s0A[par][0][k], s1B[1][k], acc[0][3]);                    \
    acc[1][2] = MF(s0A[par][1][k], s1B[0][k], acc[1][2]);                    \
    acc[1][3] = MF(s0A[par][1][k], s1B[1][k], acc[1][3]);                    \
    acc[2][0] = MF(s1A[0][k], s0B[par][0][k], acc[2][0]);                    \
    acc[2][1] = MF(s1A[0][k], s0B[par][1][k], acc[2][1]);                    \
    acc[3][0] = MF(s1A[1][k], s0B[par][0][k], acc[3][0]);                    \
    acc[3][1] = MF(s1A[1][k], s0B[par][1][k], acc[3][1]);                    \
} while (0)
#define G1(par) do { G1K(par, 0); G1K(par, 1); } while (0)

#define G2K(par, k) do {                                                     \
    acc[2][2] = MF(s1A[0][k], s1B[0][k], acc[2][2]);                         \
    acc[2][3] = MF(s1A[0][k], s1B[1][k], acc[2][3]);                         \
    acc[3][2] = MF(s1A[1][k], s1B[0][k], acc[3][2]);                         \
    acc[3][3] = MF(s1A[1][k], s1B[1][k], acc[3][3]);                         \
    acc[4][0] = MF(s2A[k], s0B[par][0][k], acc[4][0]);                       \
    acc[4][1] = MF(s2A[k], s0B[par][1][k], acc[4][1]);                       \
    acc[4][2] = MF(s2A[k], s1B[0][k], acc[4][2]);                            \
    acc[4][3] = MF(s2A[k], s1B[1][k], acc[4][3]);                            \
} while (0)
#define G2(par) do { G2K(par, 0); G2K(par, 1); } while (0)

#define FENCE() asm volatile("" ::: "memory")
#define BARRIER() do { FENCE(); __builtin_amdgcn_s_barrier(); FENCE(); } while (0)
#define VMW9()  asm volatile("s_waitcnt vmcnt(9)" ::: "memory")
#define VMW0()  asm volatile("s_waitcnt vmcnt(0)" ::: "memory")
#define LGKM0() asm volatile("s_waitcnt lgkmcnt(0)" ::: "memory")

// one K-tile: T runtime (uniform scalar), par literal
#define TILE(par, T) do {                                                    \
    PRE_S1(par);                                                             \
    __builtin_amdgcn_s_setprio(1); G0(par); __builtin_amdgcn_s_setprio(0);   \
    PRE_S2(par);                                                             \
    __builtin_amdgcn_s_setprio(1); G1(par); __builtin_amdgcn_s_setprio(0);   \
    if ((T) < 30) {                                                          \
        LGKM0();                                                             \
        BARRIER();            /* all waves' buf[par] reads drained */        \
        STG_A(par, (T) + 2); STG_B(par, (T) + 2);                            \
        VMW9();               /* stage(T+1) landed (own) */                  \
        BARRIER();            /* stage(T+1) published (all waves) */         \
        PRE_S0((par) ^ 1);    /* tile T+1 operands */                        \
    } else if ((T) == 30) {                                                  \
        VMW0();               /* stage(31) landed (own) */                   \
        BARRIER();            /* published */                                \
        PRE_S0(1);                                                           \
    }                                                                        \
    __builtin_amdgcn_s_setprio(1); G2(par); __builtin_amdgcn_s_setprio(0);   \
} while (0)

__global__ __launch_bounds__(256, 2) void gemm_bt(const u16* __restrict__ A,
                                                  const u16* __restrict__ B,
                                                  __hip_bfloat16* __restrict__ C) {
    __shared__ __align__(16) u16 As[2 * 160 * 64];
    __shared__ __align__(16) u16 Bs[2 * 128 * 64];

    int orig = blockIdx.x;
    int wgid = (orig & 7) * 64 + (orig >> 3);
    int nt = wgid >> 4, mt = wgid & 15;    // nt 0..31, mt 0..15
    int m0 = mt * 160, n0 = nt * 128;

    int t = threadIdx.x;
    int w = t >> 6, L = t & 63;          // wave 0..3, lane
    int wm = w >> 1, wn = w & 1;         // wave grid 2M x 2N, per-wave 80x64
    int q = L >> 4, lm = L & 15;         // MFMA lane decomposition
    int lr = L >> 3, ls = L & 7;         // staging lane decomposition

    int csw = (ls ^ lr) * 8;
    const u16* gA0 = A + (size_t)(m0 + lr) * K_DIM + csw;
    const u16* gB0 = B + (size_t)(n0 + lr) * K_DIM + csw;

    int sw = (lm & 7) << 3;
    int arow = (wm * 80 + lm) * 64;
    int brow = (wn * 64 + lm) * 64;
    int col[2] = { (q * 8) ^ sw, (32 + q * 8) ^ sw };

    floatx4 acc[5][4];
    floatx4 z = {0.f, 0.f, 0.f, 0.f};
#pragma unroll
    for (int i = 0; i < 5; ++i)
#pragma unroll
        for (int j = 0; j < 4; ++j) acc[i][j] = z;

    short8 s0A[2][2][2], s0B[2][2][2];   // [parity][frag][ks]
    short8 s1A[2][2], s1B[2][2];         // [frag][ks]
    short8 s2A[2];                       // [ks]

    // ---- prologue: tile0 -> buf0, tile1 -> buf1 (in flight) ----
    STG_A(0, 0); STG_B(0, 0);            // 9
    STG_A(1, 1); STG_B(1, 1);            // 9 -> 18 outstanding
    VMW9();                              // tile0 landed; keep tile1's 9
    BARRIER();
    PRE_S0(0);                           // tile0 s0 operands

    for (int it = 0; it < 16; ++it) {
        TILE(0, 2 * it);
        TILE(1, 2 * it + 1);
    }

    // ---- C-write. C/D layout: col=lane&15, row=(lane>>4)*4+reg ----
    if (m0 + 159 < H_ROWS) {
#pragma unroll
        for (int mi = 0; mi < 5; ++mi) {
            int gm = m0 + wm * 80 + mi * 16 + q * 4;
#pragma unroll
            for (int ni = 0; ni < 4; ++ni) {
                int gn = n0 + wn * 64 + ni * 16 + lm;
#pragma unroll
                for (int r = 0; r < 4; ++r)
                    C[(size_t)(gm + r) * NPIX + gn] = __float2bfloat16(acc[mi][ni][r]);
            }
        }
    } else {
#pragma unroll
        for (int mi = 0; mi < 5; ++mi) {
            int gm = m0 + wm * 80 + mi * 16 + q * 4;
#pragma unroll
            for (int ni = 0; ni < 4; ++ni) {
                int gn = n0 + wn * 64 + ni * 16 + lm;
#pragma unroll
                for (int r = 0; r < 4; ++r) {
                    int row = gm + r;
                    if (row < H_ROWS)
                        C[(size_t)row * NPIX + gn] = __float2bfloat16(acc[mi][ni][r]);
                }
            }
        }
    }
}

// ---------------- sigma_raw (conv rows of H) + BN stats (R7-validated, R6 version) ----------------
__global__ void sigma_stats(const __hip_bfloat16* __restrict__ Hm, float* __restrict__ sraw,
                            float* __restrict__ stats) {
    int b = blockIdx.x;           // (n*9 + l)*4 + quarter
    int qq = b & 3, nl = b >> 2;
    int n = nl / 9, l = nl - n * 9;
    int t = threadIdx.x;
    int pix = qq * 256 + t;
    int y = pix >> 5, x = pix & 31;
    float v = 0.f;
#pragma unroll
    for (int k = 0; k < 9; ++k) {
        int yy = y + k / 3 - 1, xx = x + (k % 3) - 1;
        if (yy >= 0 && yy < 32 && xx >= 0 && xx < 32)
            v += __bfloat162float(Hm[(size_t)(2304 + k * 9 + l) * NPIX + n * HW + yy * 32 + xx]);
    }
    sraw[(size_t)nl * HW + pix] = v;
    __shared__ float r1[256], r2[256];
    r1[t] = v; r2[t] = v * v;
    __syncthreads();
    for (int s = 128; s > 0; s >>= 1) {
        if (t < s) { r1[t] += r1[t + s]; r2[t] += r2[t + s]; }
        __syncthreads();
    }
    if (t == 0) { atomicAdd(&stats[l], r1[0]); atomicAdd(&stats[9 + l], r2[0]); }
}

// ---------------- tail v3 (R6-measured-best version, restored verbatim) ----------------
// grid 1024: b = n*256 + ph*128 + og; channels o = 2*og,2*og+1; pixels ph*512 + i*256 + t (i=0,1)
__global__ void tail(const __hip_bfloat16* __restrict__ Hm, const float* __restrict__ sraw,
                     const float* __restrict__ stats, const float* __restrict__ gamma,
                     const float* __restrict__ beta, float* __restrict__ out) {
    int b = blockIdx.x;
    int n = b >> 8, rem = b & 255;
    int ph = rem >> 7, og = rem & 127;
    int t = threadIdx.x;
    float mean[9], istd[9], gg[9], bb[9];
#pragma unroll
    for (int l = 0; l < 9; ++l) {
        float m = stats[l] * (1.f / 4096.f);
        float var = stats[9 + l] * (1.f / 4096.f) - m * m;
        mean[l] = m; istd[l] = rsqrtf(var + BN_EPS);
        gg[l] = gamma[l]; bb[l] = beta[l];
    }
    const __hip_bfloat16* hb = Hm + (size_t)(og * 2) * NPIX + (size_t)n * HW;
    float* ob = out + ((size_t)n * 256 + og * 2) * HW;
#pragma unroll
    for (int i = 0; i < 2; ++i) {
        int pix = ph * 512 + i * 256 + t;
        int y = pix >> 5, x = pix & 31;
        float v[9];
        float mx = -1e30f;
#pragma unroll
        for (int l = 0; l < 9; ++l) {
            float tv = (sraw[(size_t)(n * 9 + l) * HW + pix] - mean[l]) * istd[l];
            tv = tv * gg[l] + bb[l];
            v[l] = tv; mx = fmaxf(mx, tv);
        }
        float ssum = 0.f;
#pragma unroll
        for (int l = 0; l < 9; ++l) { v[l] = __expf(v[l] - mx); ssum += v[l]; }
        float inv = 1.f / ssum;
        float acc0 = 0.f, acc1 = 0.f;
#pragma unroll
        for (int l = 0; l < 9; ++l) {
            int dy = l / 3 - 1, dx = l % 3 - 1;
            int yy = y + dy, xx = x + dx;
            if (yy >= 0 && yy < 32 && xx >= 0 && xx < 32) {
                float sv = v[l] * inv;
                size_t hidx = (size_t)(l * 256) * NPIX + (size_t)(pix + dy * 32 + dx);
                acc0 += sv * __bfloat162float(hb[hidx]);
                acc1 += sv * __bfloat162float(hb[hidx + NPIX]);
            }
        }
        ob[pix] = acc0;
        ob[HW + pix] = acc1;
    }
}

extern "C" void kernel_launch(void* const* d_in, const int* in_sizes, int n_in,
                              void* d_out, int out_size, void* d_ws, size_t ws_size,
                              hipStream_t stream) {
    const float* x     = (const float*)d_in[0];
    const float* cw    = (const float*)d_in[1];
    const float* gamma = (const float*)d_in[2];
    const float* beta  = (const float*)d_in[3];
    const float* wgt   = (const float*)d_in[4];

    char* ws = (char*)d_ws;
    u16*   Abuf = (u16*)(ws + OFF_A);
    u16*   XT   = (u16*)(ws + OFF_XT);
    u16*   Hm   = (u16*)(ws + OFF_H);
    float* sraw = (float*)(ws + OFF_SRAW);
    float* stats= (float*)(ws + OFF_STAT);

    build_all<<<2314, 256, 0, stream>>>(x, wgt, cw, XT, Abuf, stats);
    gemm_bt<<<512, 256, 0, stream>>>(Abuf, XT, (__hip_bfloat16*)Hm);
    sigma_stats<<<N_IMG * KK * 4, 256, 0, stream>>>((const __hip_bfloat16*)Hm, sraw, stats);
    tail<<<1024, 256, 0, stream>>>((const __hip_bfloat16*)Hm, sraw, stats, gamma, beta, (float*)d_out);
}

// Round 10
// 156.367 us; speedup vs baseline: 1.0440x; 1.0055x over previous
//
#include <hip/hip_runtime.h>
#include <hip/hip_bf16.h>
#include <stdint.h>

typedef unsigned short u16;
typedef __attribute__((ext_vector_type(8))) short short8;
typedef __attribute__((ext_vector_type(4))) float floatx4;

#define N_IMG 4
#define C_IN  2048
#define HW    1024
#define KK    9
#define O_OUT 256
#define NPIX  4096          // N_IMG*HW
#define M_PAD  2560         // 16 M-tiles x 160 rows (2304 proj + 81 conv + pad)
#define H_ROWS 2432         // H rows actually stored (proj 2304 + conv 81 + pad)
#define K_DIM  2048
#define BN_EPS 1e-5f

// workspace offsets (bytes), 256-aligned
#define OFF_A    0u                // A: 2560*2048*2 = 10485760
#define OFF_XT   10485760u         // XT: 4096*2048*2 = 16777216
#define OFF_H    27262976u         // H: 2432*4096*2 = 19922944
#define OFF_SRAW 47185920u         // sraw: 36864*4
#define OFF_STAT 47333376u

// fp32 -> bf16 bits, round-to-nearest-even
__device__ __forceinline__ u16 f2b(float f) {
    unsigned u = __float_as_uint(f);
    return (u16)((u + 0x7FFFu + ((u >> 16) & 1u)) >> 16);
}

__device__ __forceinline__ void load8f(const float* base, size_t eidx, u16* out) {
    const float* p = base + eidx;
    float4 a = ((const float4*)p)[0];
    float4 b = ((const float4*)p)[1];
    float f[8] = {a.x, a.y, a.z, a.w, b.x, b.y, b.z, b.w};
#pragma unroll
    for (int j = 0; j < 8; ++j) out[j] = f2b(f[j]);
}

// ---------------- merged staging kernel (R10-validated, unchanged) ----------------
__global__ void build_all(const float* __restrict__ x, const float* __restrict__ wgt,
                          const float* __restrict__ cw, u16* __restrict__ xt,
                          u16* __restrict__ A, float* __restrict__ stats) {
    __shared__ __align__(16) u16 lds[9 * 2056];
    int b = blockIdx.x, t = threadIdx.x;
    if (b < 2048) {
        int c0 = (b & 31) * 64, p0 = ((b >> 5) & 15) * 64, n = b >> 9;
        int rp = t >> 3;                // channel-pair 0..31
        int pv = (t & 7) * 8;           // pixel group
        u16 h0[8], h1[8];
        load8f(x, (size_t)(n * C_IN + c0 + 2 * rp) * HW + p0 + pv, h0);
        load8f(x, (size_t)(n * C_IN + c0 + 2 * rp + 1) * HW + p0 + pv, h1);
        unsigned* l32 = (unsigned*)lds;   // [64 pixels][stride 35 u32]
#pragma unroll
        for (int j = 0; j < 8; ++j)
            l32[(pv + j) * 35 + rp] = (unsigned)h0[j] | ((unsigned)h1[j] << 16);
        __syncthreads();
        int pr = t >> 3, cq = (t & 7) * 4;   // pixel, u32-quad (8 channels)
        unsigned o0[4], o1[4];
#pragma unroll
        for (int i = 0; i < 4; ++i) {
            o0[i] = l32[pr * 35 + cq + i];
            o1[i] = l32[(pr + 32) * 35 + cq + i];
        }
        *(uint4*)(xt + (size_t)(n * HW + p0 + pr) * K_DIM + c0 + cq * 2) = *(uint4*)o0;
        *(uint4*)(xt + (size_t)(n * HW + p0 + pr + 32) * K_DIM + c0 + cq * 2) = *(uint4*)o1;
    } else if (b < 2304) {
        int o = b - 2048;
        size_t base = (size_t)o * 18432;   // weight[o][c][l], e = c*9+l
        for (int i = 0; i < 9; ++i) {
            int e0 = (t + i * 256) * 8;
            u16 hv[8];
            load8f(wgt, base + e0, hv);
#pragma unroll
            for (int j = 0; j < 8; ++j) {
                int e = e0 + j;
                int c = e / 9, l = e - c * 9;
                lds[l * 2056 + c] = hv[j];
            }
        }
        __syncthreads();
        for (int l = 0; l < 9; ++l) {
            size_t row = (size_t)l * 256 + o;
            *(uint4*)(A + row * K_DIM + t * 8) = *(const uint4*)&lds[l * 2056 + t * 8];
        }
    } else if (b < 2313) {
        int l = b - 2304;
        size_t base = (size_t)l * 18432;    // conv_w[l][c][k], e = c*9+k
        for (int i = 0; i < 9; ++i) {
            int e0 = (t + i * 256) * 8;
            u16 hv[8];
            load8f(cw, base + e0, hv);
#pragma unroll
            for (int j = 0; j < 8; ++j) {
                int e = e0 + j;
                int c = e / 9, k = e - c * 9;
                lds[k * 2056 + c] = hv[j];
            }
        }
        __syncthreads();
        for (int k = 0; k < 9; ++k) {
            size_t row = 2304 + (size_t)k * 9 + l;
            *(uint4*)(A + row * K_DIM + t * 8) = *(const uint4*)&lds[k * 2056 + t * 8];
        }
    } else {
        // zero A rows 2385..2431 (rows 2432..2559 are garbage; each H row
        // depends only on its own A row and rows >=2432 are never stored;
        // garbage/valid rows never share an MFMA fragment since 2432%16==0)
        uint4 z = {0, 0, 0, 0};
        uint4* dst = (uint4*)(A + (size_t)2385 * K_DIM);
        for (int i = t; i < (47 * 2048) / 8; i += 256) dst[i] = z;
        if (t < 18) stats[t] = 0.0f;
    }
}

// ---------------- GEMM: H = A * XT^T (R16, session-best: 43.8-46.6us, MfmaUtil 36-39%) ----------------
// 160x128 tile, BK=64, 4 waves (2Mx2N, per-wave 80x64), grid 16x32=512
// -> 2 independent blocks per CU (LDS 72KB/block, launch_bounds(256,2)).
// Two co-resident blocks are never barrier-coupled: one block's MFMAs cover
// the other's read/stage/DMA-wait windows. Counted-vmcnt ledger: VMW9 =
// keep newest stage pair (B[4]+A[5]), drains the previous tile's stages.
__device__ __forceinline__ void gload_lds16(const void* g, void* l) {
    __builtin_amdgcn_global_load_lds((__attribute__((address_space(1))) void*)(g),
                                     (__attribute__((address_space(3))) void*)(l), 16, 0, 0);
}

#define STG_A(bb, kt) do {                                                                   \
    _Pragma("unroll") for (int j_ = 0; j_ < 5; ++j_) {                                       \
        int qd_ = w + 4 * j_;                                                                \
        gload_lds16(gA0 + (size_t)(qd_ * 8) * K_DIM + (size_t)(kt) * 64,                     \
                    As + (bb) * 10240 + qd_ * 512);                                          \
    }                                                                                        \
} while (0)

#define STG_B(bb, kt) do {                                                                   \
    _Pragma("unroll") for (int j_ = 0; j_ < 4; ++j_) {                                       \
        int qd_ = w + 4 * j_;                                                                \
        gload_lds16(gB0 + (size_t)(qd_ * 8) * K_DIM + (size_t)(kt) * 64,                     \
                    Bs + (bb) * 8192 + qd_ * 512);                                           \
    }                                                                                        \
} while (0)

#define RD_A(bb, mi, ks) (*(const short8*)(As + (bb) * 10240 + arow + (mi) * 1024 + col[ks]))
#define RD_B(bb, ni, ks) (*(const short8*)(Bs + (bb) * 8192 + brow + (ni) * 1024 + col[ks]))

#define MF(a, b, c) __builtin_amdgcn_mfma_f32_16x16x32_bf16(a, b, c, 0, 0, 0)

#define COMPUTE(par) do {                                                                    \
    bq[0][0] = RD_B(par, 0, 0); bq[1][0] = RD_B(par, 1, 0);                                  \
    bq[2][0] = RD_B(par, 2, 0); bq[3][0] = RD_B(par, 3, 0);                                  \
    aq[0][0] = RD_A(par, 0, 0); aq[1][0] = RD_A(par, 1, 0);                                  \
    aq[2][0] = RD_A(par, 2, 0); aq[3][0] = RD_A(par, 3, 0);                                  \
    aq[4][0] = RD_A(par, 4, 0);                                                              \
    bq[0][1] = RD_B(par, 0, 1); bq[1][1] = RD_B(par, 1, 1);                                  \
    bq[2][1] = RD_B(par, 2, 1); bq[3][1] = RD_B(par, 3, 1);                                  \
    aq[0][1] = RD_A(par, 0, 1); aq[1][1] = RD_A(par, 1, 1);                                  \
    aq[2][1] = RD_A(par, 2, 1); aq[3][1] = RD_A(par, 3, 1);                                  \
    aq[4][1] = RD_A(par, 4, 1);                                                              \
    __builtin_amdgcn_s_setprio(1);                                                           \
    _Pragma("unroll") for (int ks_ = 0; ks_ < 2; ++ks_)                                      \
      _Pragma("unroll") for (int mi_ = 0; mi_ < 5; ++mi_)                                    \
        _Pragma("unroll") for (int ni_ = 0; ni_ < 4; ++ni_)                                  \
          acc[mi_][ni_] = MF(aq[mi_][ks_], bq[ni_][ks_], acc[mi_][ni_]);                     \
    __builtin_amdgcn_s_setprio(0);                                                           \
} while (0)

#define FENCE() asm volatile("" ::: "memory")
#define BARRIER() do { FENCE(); __builtin_amdgcn_s_barrier(); FENCE(); } while (0)
#define VMW9() asm volatile("s_waitcnt vmcnt(9)" ::: "memory")
#define VMW0() asm volatile("s_waitcnt vmcnt(0)" ::: "memory")

__global__ __launch_bounds__(256, 2) void gemm_bt(const u16* __restrict__ A,
                                                  const u16* __restrict__ B,
                                                  __hip_bfloat16* __restrict__ C) {
    __shared__ __align__(16) u16 As[2 * 160 * 64];
    __shared__ __align__(16) u16 Bs[2 * 128 * 64];

    int orig = blockIdx.x;
    int wgid = (orig & 7) * 64 + (orig >> 3);
    int nt = wgid >> 4, mt = wgid & 15;    // nt 0..31, mt 0..15
    int m0 = mt * 160, n0 = nt * 128;

    int t = threadIdx.x;
    int w = t >> 6, L = t & 63;          // wave 0..3, lane
    int wm = w >> 1, wn = w & 1;         // wave grid 2M x 2N, per-wave 80x64
    int q = L >> 4, lm = L & 15;         // MFMA lane decomposition
    int lr = L >> 3, ls = L & 7;         // staging lane decomposition

    int csw = (ls ^ lr) * 8;
    const u16* gA0 = A + (size_t)(m0 + lr) * K_DIM + csw;
    const u16* gB0 = B + (size_t)(n0 + lr) * K_DIM + csw;

    int sw = (lm & 7) << 3;
    int arow = (wm * 80 + lm) * 64;
    int brow = (wn * 64 + lm) * 64;
    int col[2] = { (q * 8) ^ sw, (32 + q * 8) ^ sw };

    floatx4 acc[5][4];
    floatx4 z = {0.f, 0.f, 0.f, 0.f};
#pragma unroll
    for (int i = 0; i < 5; ++i)
#pragma unroll
        for (int j = 0; j < 4; ++j) acc[i][j] = z;

    short8 aq[5][2], bq[4][2];

    STG_A(0, 0); STG_B(0, 0);            // 9
    STG_B(1, 1); STG_A(1, 1);            // 9 -> 18 outstanding
    VMW9();                              // drain tile0 (A+B); keep tile1's 9
    BARRIER();

    for (int it = 0; it < 15; ++it) {
        int T = 2 * it;
        COMPUTE(0);                      // tile T from buf0
        BARRIER();
        STG_B(0, T + 2); STG_A(0, T + 2);   // 9 -> buf0
        VMW9();                          // drain tile T+1's 9; keep new 9
        BARRIER();
        COMPUTE(1);                      // tile T+1 from buf1
        BARRIER();
        if (it < 14) {
            STG_B(1, T + 3); STG_A(1, T + 3);  // 9 -> buf1
            VMW9();
            BARRIER();
        }
    }
    VMW0(); BARRIER();                   // tile 30 landed everywhere
    COMPUTE(0);                          // tile 30
    BARRIER();
    STG_B(1, 31); STG_A(1, 31);
    VMW0(); BARRIER();                   // tile 31 landed
    COMPUTE(1);                          // tile 31

    if (m0 + 159 < H_ROWS) {
#pragma unroll
        for (int mi = 0; mi < 5; ++mi) {
            int gm = m0 + wm * 80 + mi * 16 + q * 4;
#pragma unroll
            for (int ni = 0; ni < 4; ++ni) {
                int gn = n0 + wn * 64 + ni * 16 + lm;
#pragma unroll
                for (int r = 0; r < 4; ++r)
                    C[(size_t)(gm + r) * NPIX + gn] = __float2bfloat16(acc[mi][ni][r]);
            }
        }
    } else {
#pragma unroll
        for (int mi = 0; mi < 5; ++mi) {
            int gm = m0 + wm * 80 + mi * 16 + q * 4;
#pragma unroll
            for (int ni = 0; ni < 4; ++ni) {
                int gn = n0 + wn * 64 + ni * 16 + lm;
#pragma unroll
                for (int r = 0; r < 4; ++r) {
                    int row = gm + r;
                    if (row < H_ROWS)
                        C[(size_t)row * NPIX + gn] = __float2bfloat16(acc[mi][ni][r]);
                }
            }
        }
    }
}

// ---------------- sigma_raw (conv rows of H) + BN stats (R7-validated, R6 version) ----------------
__global__ void sigma_stats(const __hip_bfloat16* __restrict__ Hm, float* __restrict__ sraw,
                            float* __restrict__ stats) {
    int b = blockIdx.x;           // (n*9 + l)*4 + quarter
    int qq = b & 3, nl = b >> 2;
    int n = nl / 9, l = nl - n * 9;
    int t = threadIdx.x;
    int pix = qq * 256 + t;
    int y = pix >> 5, x = pix & 31;
    float v = 0.f;
#pragma unroll
    for (int k = 0; k < 9; ++k) {
        int yy = y + k / 3 - 1, xx = x + (k % 3) - 1;
        if (yy >= 0 && yy < 32 && xx >= 0 && xx < 32)
            v += __bfloat162float(Hm[(size_t)(2304 + k * 9 + l) * NPIX + n * HW + yy * 32 + xx]);
    }
    sraw[(size_t)nl * HW + pix] = v;
    __shared__ float r1[256], r2[256];
    r1[t] = v; r2[t] = v * v;
    __syncthreads();
    for (int s = 128; s > 0; s >>= 1) {
        if (t < s) { r1[t] += r1[t + s]; r2[t] += r2[t + s]; }
        __syncthreads();
    }
    if (t == 0) { atomicAdd(&stats[l], r1[0]); atomicAdd(&stats[9 + l], r2[0]); }
}

// ---------------- tail v3 (R6-measured-best version) ----------------
// grid 1024: b = n*256 + ph*128 + og; channels o = 2*og,2*og+1; pixels ph*512 + i*256 + t (i=0,1)
__global__ void tail(const __hip_bfloat16* __restrict__ Hm, const float* __restrict__ sraw,
                     const float* __restrict__ stats, const float* __restrict__ gamma,
                     const float* __restrict__ beta, float* __restrict__ out) {
    int b = blockIdx.x;
    int n = b >> 8, rem = b & 255;
    int ph = rem >> 7, og = rem & 127;
    int t = threadIdx.x;
    float mean[9], istd[9], gg[9], bb[9];
#pragma unroll
    for (int l = 0; l < 9; ++l) {
        float m = stats[l] * (1.f / 4096.f);
        float var = stats[9 + l] * (1.f / 4096.f) - m * m;
        mean[l] = m; istd[l] = rsqrtf(var + BN_EPS);
        gg[l] = gamma[l]; bb[l] = beta[l];
    }
    const __hip_bfloat16* hb = Hm + (size_t)(og * 2) * NPIX + (size_t)n * HW;
    float* ob = out + ((size_t)n * 256 + og * 2) * HW;
#pragma unroll
    for (int i = 0; i < 2; ++i) {
        int pix = ph * 512 + i * 256 + t;
        int y = pix >> 5, x = pix & 31;
        float v[9];
        float mx = -1e30f;
#pragma unroll
        for (int l = 0; l < 9; ++l) {
            float tv = (sraw[(size_t)(n * 9 + l) * HW + pix] - mean[l]) * istd[l];
            tv = tv * gg[l] + bb[l];
            v[l] = tv; mx = fmaxf(mx, tv);
        }
        float ssum = 0.f;
#pragma unroll
        for (int l = 0; l < 9; ++l) { v[l] = __expf(v[l] - mx); ssum += v[l]; }
        float inv = 1.f / ssum;
        float acc0 = 0.f, acc1 = 0.f;
#pragma unroll
        for (int l = 0; l < 9; ++l) {
            int dy = l / 3 - 1, dx = l % 3 - 1;
            int yy = y + dy, xx = x + dx;
            if (yy >= 0 && yy < 32 && xx >= 0 && xx < 32) {
                float sv = v[l] * inv;
                size_t hidx = (size_t)(l * 256) * NPIX + (size_t)(pix + dy * 32 + dx);
                acc0 += sv * __bfloat162float(hb[hidx]);
                acc1 += sv * __bfloat162float(hb[hidx + NPIX]);
            }
        }
        ob[pix] = acc0;
        ob[HW + pix] = acc1;
    }
}

extern "C" void kernel_launch(void* const* d_in, const int* in_sizes, int n_in,
                              void* d_out, int out_size, void* d_ws, size_t ws_size,
                              hipStream_t stream) {
    const float* x     = (const float*)d_in[0];
    const float* cw    = (const float*)d_in[1];
    const float* gamma = (const float*)d_in[2];
    const float* beta  = (const float*)d_in[3];
    const float* wgt   = (const float*)d_in[4];

    char* ws = (char*)d_ws;
    u16*   Abuf = (u16*)(ws + OFF_A);
    u16*   XT   = (u16*)(ws + OFF_XT);
    u16*   Hm   = (u16*)(ws + OFF_H);
    float* sraw = (float*)(ws + OFF_SRAW);
    float* stats= (float*)(ws + OFF_STAT);

    build_all<<<2314, 256, 0, stream>>>(x, wgt, cw, XT, Abuf, stats);
    gemm_bt<<<512, 256, 0, stream>>>(Abuf, XT, (__hip_bfloat16*)Hm);
    sigma_stats<<<N_IMG * KK * 4, 256, 0, stream>>>((const __hip_bfloat16*)Hm, sraw, stats);
    tail<<<1024, 256, 0, stream>>>((const __hip_bfloat16*)Hm, sraw, stats, gamma, beta, (float*)d_out);
}